// Round 13
// baseline (373.714 us; speedup 1.0000x reference)
//
#include <hip/hip_runtime.h>
#include <hip/hip_bf16.h>
#include <stdint.h>

// Capsule routing, f32 in/out. B=32, Nin=2048, Din=16, Nout=64, Dout=32, 3 iters.
// Round 13: per-i IT structure (1x L3 W-read; phase-C W re-read is L2-hot at
// 64KB/i) + c_lds DOUBLE-BUFFER -> 2 barriers per i (A-visible, B-visible; C(i)
// overlaps A(i+1) on the other buffer) + c folded into MFMA B-operand in C.
// Pass0 (fused f32->bf16 W transcode + uniform-c accumulate) unchanged.

#define CB    32
#define NIN   2048
#define DIN   16
#define NOUT  64
#define DOUT  32
#define IPB   8
#define NCB   (NIN / IPB)            // 256 blocks, 1/CU
#define WI    (NOUT * DOUT * DIN)    // 32768 elements per i
#define WELEM ((size_t)NIN * WI)

typedef __attribute__((ext_vector_type(8)))  short bf16x8;
typedef __attribute__((ext_vector_type(16))) float f32x16;
typedef _Float16 h2 __attribute__((ext_vector_type(2)));

// IT LDS: c dbuf [2][64][33] f32 = 16896 | x [8i*32b][10] u32 = 10240
#define CSTRIDE 2112                 // 64*33
#define XOFF_IT 16896
#define SMEM_IT 27136
#define SMEM_P0 10240

static __device__ __forceinline__ uint32_t pack_bf2(float a, float b) {
    __hip_bfloat162 hh = __float22bfloat162_rn(make_float2(a, b));
    uint32_t u; __builtin_memcpy(&u, &hh, 4); return u;
}
static __device__ __forceinline__ uint16_t f2bf(float v) {
    return (uint16_t)(pack_bf2(v, 0.f) & 0xffffu);
}
static __device__ __forceinline__ float bf2f(uint16_t u) {
    uint32_t v = (uint32_t)u << 16; float f; __builtin_memcpy(&f, &v, 4); return f;
}
static __device__ __forceinline__ uint32_t pack_h2(float a, float b) {
    h2 r; r.x = (_Float16)a; r.y = (_Float16)b;
    uint32_t u; __builtin_memcpy(&u, &r, 4); return u;
}
static __device__ __forceinline__ h2 as_h2(uint32_t u) {
    h2 r; __builtin_memcpy(&r, &u, 4); return r;
}
static __device__ __forceinline__ float bflo(uint32_t u) {
    uint32_t v = u << 16; float f; __builtin_memcpy(&f, &v, 4); return f;
}
static __device__ __forceinline__ float bfhi(uint32_t u) {
    uint32_t v = u & 0xffff0000u; float f; __builtin_memcpy(&f, &v, 4); return f;
}

// ---------------- Pass 0: uniform coupling; streams f32 W, emits bf16 W ----------------
// Block cb owns i in [cb*8, +8), all 32 b. 16 waves, wave w owns j in [4w, 4w+4).
// Lane: bl = l&31, h = l>>5. A-frag: W[i][j*32+bl][8h..8h+8); B-frag: x[bl][i][8h..8h+8).
__global__ __launch_bounds__(1024, 1) void caps_pass0(
    const float* __restrict__ x, const float* __restrict__ Wf,
    uint32_t* __restrict__ WhOut, uint16_t* __restrict__ s_partial)
{
    extern __shared__ char smem[];
    uint32_t* x_lds = (uint32_t*)smem;             // [8i*32b][10]

    const int cb = blockIdx.x;
    const int t  = threadIdx.x;
    const int w  = t >> 6, l = t & 63;
    const int bl = l & 31, h = l >> 5;
    const int j0 = w * 4;

    {
        const int b = t >> 5, i = (t >> 2) & 7, k4 = (t & 3) * 4;
        const float4 xv = *(const float4*)(x + ((size_t)b * NIN + cb * IPB + i) * DIN + k4);
        x_lds[(i * 32 + b) * 10 + (k4 >> 1)]     = pack_bf2(xv.x, xv.y);
        x_lds[(i * 32 + b) * 10 + (k4 >> 1) + 1] = pack_bf2(xv.z, xv.w);
    }
    __syncthreads();

    f32x16 sacc[4];
#pragma unroll
    for (int jj = 0; jj < 4; ++jj) sacc[jj] = (f32x16)0.0f;

#pragma unroll 1
    for (int i = 0; i < IPB; ++i) {
        const size_t wbase = (size_t)(cb * IPB + i) * WI;
        bf16x8 bfr;
        {
            uint32_t uu[4];
            const uint32_t* xp = &x_lds[(i * 32 + bl) * 10 + h * 4];
            uu[0] = xp[0]; uu[1] = xp[1]; uu[2] = xp[2]; uu[3] = xp[3];
            __builtin_memcpy(&bfr, uu, 16);
        }
#pragma unroll
        for (int jj = 0; jj < 4; ++jj) {
            const int j = j0 + jj;
            const size_t eoff = wbase + (size_t)(j * 32 + bl) * 16 + h * 8;
            const float4* wp = (const float4*)(Wf + eoff);
            const float4 a4 = wp[0], b4 = wp[1];
            uint32_t uu[4];
            uu[0] = pack_bf2(a4.x, a4.y); uu[1] = pack_bf2(a4.z, a4.w);
            uu[2] = pack_bf2(b4.x, b4.y); uu[3] = pack_bf2(b4.z, b4.w);
            bf16x8 afr; __builtin_memcpy(&afr, uu, 16);
            uint4 st; st.x = uu[0]; st.y = uu[1]; st.z = uu[2]; st.w = uu[3];
            *(uint4*)(WhOut + (eoff >> 1)) = st;
            sacc[jj] = __builtin_amdgcn_mfma_f32_32x32x16_bf16(afr, bfr, sacc[jj], 0, 0, 0);
        }
    }

#pragma unroll
    for (int jj = 0; jj < 4; ++jj) {
        const int j = j0 + jj;
#pragma unroll
        for (int r = 0; r < 16; ++r) {
            const int d = (r & 3) + 8 * (r >> 2) + 4 * h;
            s_partial[(size_t)cb * (2048 * 32) + (size_t)(j * 32 + d) * 32 + bl] =
                f2bf(sacc[jj][r] * (1.0f / 64.0f));
        }
    }
}

// ---------------- IT passes: per-i, double-buffered c_lds, 2 barriers/i ----------------
template <int IT>
__global__ __launch_bounds__(1024, 1) void caps_it(
    const float* __restrict__ x, const uint16_t* __restrict__ Wh,
    const float* __restrict__ v_prev, const float* __restrict__ blog_in,
    float* __restrict__ blog_out, uint16_t* __restrict__ s_partial)
{
    extern __shared__ char smem[];
    float*    c_lds = (float*)smem;                    // [2][64][33]
    uint32_t* x_lds = (uint32_t*)(smem + XOFF_IT);     // [8i*32b][10]

    const int cb = blockIdx.x;
    const int t  = threadIdx.x;
    const int w  = t >> 6, l = t & 63;
    const int bl = l & 31, h = l >> 5;
    const int j0 = w * 4;

    // ---- stage x -> bf16 pairs ----
    {
        const int b = t >> 5, i = (t >> 2) & 7, k4 = (t & 3) * 4;
        const float4 xv = *(const float4*)(x + ((size_t)b * NIN + cb * IPB + i) * DIN + k4);
        x_lds[(i * 32 + b) * 10 + (k4 >> 1)]     = pack_bf2(xv.x, xv.y);
        x_lds[(i * 32 + b) * 10 + (k4 >> 1) + 1] = pack_bf2(xv.z, xv.w);
    }

    // ---- v in registers: lane (bl,h) holds v[b=bl][j0..j0+4)[its 8 d-pairs] ----
    constexpr int base_dp[8] = {0, 1, 4, 5, 8, 9, 12, 13};
    uint32_t vreg[4][8];
#pragma unroll
    for (int jj = 0; jj < 4; ++jj)
#pragma unroll
        for (int rp = 0; rp < 8; ++rp) {
            const int d0 = 2 * (base_dp[rp] + 2 * h);
            const float2 vv = *(const float2*)(v_prev
                + ((size_t)bl * NOUT + j0 + jj) * DOUT + d0);
            vreg[jj][rp] = pack_h2(vv.x, vv.y);
        }
    __syncthreads();

    f32x16 sacc[4];
#pragma unroll
    for (int jj = 0; jj < 4; ++jj) sacc[jj] = (f32x16)0.0f;

#pragma unroll 1
    for (int i = 0; i < IPB; ++i) {
        const int p = (i & 1) * CSTRIDE;
        const int ig = cb * IPB + i;
        const size_t wbase = (size_t)ig * WI;

        // x pairs for this (i, b=bl): raw for C's cxf, bfr for A's MFMA
        uint32_t xu[4];
        {
            const uint32_t* xp = &x_lds[(i * 32 + bl) * 10 + h * 4];
            xu[0] = xp[0]; xu[1] = xp[1]; xu[2] = xp[2]; xu[3] = xp[3];
        }
        bf16x8 bfr; __builtin_memcpy(&bfr, xu, 16);

        // ===== PHASE A: logits for this wave's 4 j (writes c_lds[p]) =====
#pragma unroll
        for (int jj = 0; jj < 4; ++jj) {
            const int j = j0 + jj;
            const bf16x8 afr = *(const bf16x8*)(Wh + wbase + (size_t)(j * 32 + bl) * 16 + h * 8);
            const f32x16 D = __builtin_amdgcn_mfma_f32_32x32x16_bf16(afr, bfr, (f32x16)0.0f, 0, 0, 0);
            float acc = 0.f;
#pragma unroll
            for (int rp = 0; rp < 8; ++rp) {
                h2 dpk; dpk.x = (_Float16)D[2 * rp]; dpk.y = (_Float16)D[2 * rp + 1];
                acc = __builtin_amdgcn_fdot2(dpk, as_h2(vreg[jj][rp]), acc, false);
            }
            acc += __shfl_xor(acc, 32);       // combine d-halves
            if (h == 0) c_lds[p + j * 33 + bl] = acc;
        }
        __syncthreads();   // A(i) visible (also fences C(i-1) reads of buffer p^1)

        // ===== PHASE B: softmax over j — 32 b-rows, 2 per wave =====
#pragma unroll
        for (int rr = 0; rr < 2; ++rr) {
            const int b = w * 2 + rr;
            float bv = c_lds[p + l * 33 + b];
            if (IT == 2) bv += blog_in[((size_t)b * NIN + ig) * NOUT + l];
            if (IT == 1) blog_out[((size_t)b * NIN + ig) * NOUT + l] = bv;
            float m = bv;
#pragma unroll
            for (int o = 32; o; o >>= 1) m = fmaxf(m, __shfl_xor(m, o));
            const float e = __expf(bv - m);
            float s = e;
#pragma unroll
            for (int o = 32; o; o >>= 1) s += __shfl_xor(s, o);
            c_lds[p + l * 33 + b] = e / s;
        }
        __syncthreads();   // B(i) visible

        // ===== PHASE C: accumulate via c-scaled B-operand (no trailing barrier;
        //        next A(i+1) writes the other c_lds buffer) =====
#pragma unroll
        for (int jj = 0; jj < 4; ++jj) {
            const int j = j0 + jj;
            const float cv = c_lds[p + j * 33 + bl];
            uint32_t cu[4];
#pragma unroll
            for (int q = 0; q < 4; ++q)
                cu[q] = pack_bf2(bflo(xu[q]) * cv, bfhi(xu[q]) * cv);
            bf16x8 cxf; __builtin_memcpy(&cxf, cu, 16);
            const bf16x8 afr = *(const bf16x8*)(Wh + wbase + (size_t)(j * 32 + bl) * 16 + h * 8);
            sacc[jj] = __builtin_amdgcn_mfma_f32_32x32x16_bf16(afr, cxf, sacc[jj], 0, 0, 0);
        }
    }

    // ---- store partials: spart[cb][jd][b] bf16 ----
#pragma unroll
    for (int jj = 0; jj < 4; ++jj) {
        const int j = j0 + jj;
#pragma unroll
        for (int r = 0; r < 16; ++r) {
            const int d = (r & 3) + 8 * (r >> 2) + 4 * h;
            s_partial[(size_t)cb * (2048 * 32) + (size_t)(j * 32 + d) * 32 + bl] =
                f2bf(sacc[jj][r]);
        }
    }
}

// ---------------- reduce over cb + bias + squash ----------------
__global__ __launch_bounds__(256) void caps_squash(
    const uint16_t* __restrict__ sp, const float* __restrict__ bias,
    float* __restrict__ vout)
{
    const int j  = blockIdx.x >> 2;
    const int bq = blockIdx.x & 3;
    const int t  = threadIdx.x;
    const int d  = t >> 3;
    const int blq = t & 7;
    const int b  = bq * 8 + blq;

    const uint16_t* p = sp + (size_t)(j * 32 + d) * 32 + b;
    float s0 = 0.f, s1 = 0.f, s2 = 0.f, s3 = 0.f;
#pragma unroll 4
    for (int c = 0; c < NCB; c += 4) {
        s0 += bf2f(p[(size_t)(c + 0) * (2048 * 32)]);
        s1 += bf2f(p[(size_t)(c + 1) * (2048 * 32)]);
        s2 += bf2f(p[(size_t)(c + 2) * (2048 * 32)]);
        s3 += bf2f(p[(size_t)(c + 3) * (2048 * 32)]);
    }
    const float sv = ((s0 + s1) + (s2 + s3)) + bias[j * DOUT + d];

    float sq = sv * sv;
    sq += __shfl_xor(sq, 8);
    sq += __shfl_xor(sq, 16);
    sq += __shfl_xor(sq, 32);

    __shared__ float sh[4][8];
    if ((t & 63) < 8) sh[t >> 6][t & 7] = sq;
    __syncthreads();
    const float tot = sh[0][blq] + sh[1][blq] + sh[2][blq] + sh[3][blq];
    const float scale = (tot / (1.0f + tot)) * rsqrtf(tot + 1e-9f);
    vout[(size_t)b * (NOUT * DOUT) + j * DOUT + d] = scale * sv;
}

extern "C" void kernel_launch(void* const* d_in, const int* in_sizes, int n_in,
                              void* d_out, int out_size, void* d_ws, size_t ws_size,
                              hipStream_t stream) {
    const float* x    = (const float*)d_in[0];
    const float* W    = (const float*)d_in[1];
    const float* bias = (const float*)d_in[2];
    float* out = (float*)d_out;

    // ws: Wh 134.22MB | blog 16.78MB | spart(bf16) 33.55MB | vbuf 0.26MB = 184.8MB
    char* base = (char*)d_ws;
    uint32_t* Wh    = (uint32_t*)base;
    float*    blog  = (float*)(base + WELEM * 2);
    uint16_t* spart = (uint16_t*)(base + WELEM * 2 + (size_t)CB * NIN * NOUT * 4);
    float*    vbuf  = (float*)(base + WELEM * 2 + (size_t)CB * NIN * NOUT * 4
                               + (size_t)NCB * 2048 * 32 * 2);
    (void)ws_size;

    hipFuncSetAttribute(reinterpret_cast<const void*>(caps_pass0),
                        hipFuncAttributeMaxDynamicSharedMemorySize, SMEM_P0);
    hipFuncSetAttribute(reinterpret_cast<const void*>(caps_it<1>),
                        hipFuncAttributeMaxDynamicSharedMemorySize, SMEM_IT);
    hipFuncSetAttribute(reinterpret_cast<const void*>(caps_it<2>),
                        hipFuncAttributeMaxDynamicSharedMemorySize, SMEM_IT);

    caps_pass0<<<NCB, 1024, SMEM_P0, stream>>>(x, W, (uint32_t*)Wh, spart);
    caps_squash<<<NOUT * 4, 256, 0, stream>>>(spart, bias, vbuf);

    caps_it<1><<<NCB, 1024, SMEM_IT, stream>>>(x, (const uint16_t*)Wh, vbuf, nullptr, blog, spart);
    caps_squash<<<NOUT * 4, 256, 0, stream>>>(spart, bias, vbuf);

    caps_it<2><<<NCB, 1024, SMEM_IT, stream>>>(x, (const uint16_t*)Wh, vbuf, blog, nullptr, spart);
    caps_squash<<<NOUT * 4, 256, 0, stream>>>(spart, bias, out);
}

// Round 14
// 319.617 us; speedup vs baseline: 1.1693x; 1.1693x over previous
//
#include <hip/hip_runtime.h>
#include <hip/hip_bf16.h>
#include <stdint.h>

// Capsule routing, f32 in/out. B=32, Nin=2048, Din=16, Nout=64, Dout=32, 3 iters.
// Round 14: R11 skeleton (per-i phases, v in LDS, launch_bounds(1024,4), VGPR~80)
// + i-PAIRING (2 i's per phase group: 12 barriers/block instead of 24, 2x W-load
// pipeline depth in phase A) + cxf fold in phase C (c into MFMA B-operand; kills
// the f32x16 D-temp). Pass0 (fused f32->bf16 W transcode) = R11's, unchanged.

#define CB    32
#define NIN   2048
#define DIN   16
#define NOUT  64
#define DOUT  32
#define IPB   8
#define NCB   (NIN / IPB)            // 256 blocks, 1/CU
#define WI    (NOUT * DOUT * DIN)    // 32768 elements per i
#define WELEM ((size_t)NIN * WI)

typedef __attribute__((ext_vector_type(8)))  short bf16x8;
typedef __attribute__((ext_vector_type(16))) float f32x16;
typedef _Float16 h2 __attribute__((ext_vector_type(2)));

// IT LDS: v [64j*16dp][33b] u32 = 135168 | c [2][64*33] f32 = 16896 | x [256][10] u32 = 10240
#define VOFF    0
#define COFF    135168
#define CSTRIDE 2112                 // 64*33 floats
#define XOFF    152064
#define SMEM_IT 162304
#define SMEM_P0 10240

static __device__ __forceinline__ uint32_t pack_bf2(float a, float b) {
    __hip_bfloat162 hh = __float22bfloat162_rn(make_float2(a, b));
    uint32_t u; __builtin_memcpy(&u, &hh, 4); return u;
}
static __device__ __forceinline__ uint16_t f2bf(float v) {
    return (uint16_t)(pack_bf2(v, 0.f) & 0xffffu);
}
static __device__ __forceinline__ float bf2f(uint16_t u) {
    uint32_t v = (uint32_t)u << 16; float f; __builtin_memcpy(&f, &v, 4); return f;
}
static __device__ __forceinline__ uint32_t pack_h2(float a, float b) {
    h2 r; r.x = (_Float16)a; r.y = (_Float16)b;
    uint32_t u; __builtin_memcpy(&u, &r, 4); return u;
}
static __device__ __forceinline__ h2 as_h2(uint32_t u) {
    h2 r; __builtin_memcpy(&r, &u, 4); return r;
}
static __device__ __forceinline__ float bflo(uint32_t u) {
    uint32_t v = u << 16; float f; __builtin_memcpy(&f, &v, 4); return f;
}
static __device__ __forceinline__ float bfhi(uint32_t u) {
    uint32_t v = u & 0xffff0000u; float f; __builtin_memcpy(&f, &v, 4); return f;
}

// ---------------- Pass 0: uniform coupling; streams f32 W, emits bf16 W ----------------
// Block cb owns i in [cb*8, +8), all 32 b. 16 waves, wave w owns j in [4w, 4w+4).
// Lane: bl = l&31, h = l>>5. A-frag: W[i][j*32+bl][8h..8h+8); B-frag: x[bl][i][8h..8h+8).
__global__ __launch_bounds__(1024, 4) void caps_pass0(
    const float* __restrict__ x, const float* __restrict__ Wf,
    uint32_t* __restrict__ WhOut, uint16_t* __restrict__ s_partial)
{
    extern __shared__ char smem[];
    uint32_t* x_lds = (uint32_t*)smem;             // [8i*32b][10]

    const int cb = blockIdx.x;
    const int t  = threadIdx.x;
    const int w  = t >> 6, l = t & 63;
    const int bl = l & 31, h = l >> 5;
    const int j0 = w * 4;

    {
        const int b = t >> 5, i = (t >> 2) & 7, k4 = (t & 3) * 4;
        const float4 xv = *(const float4*)(x + ((size_t)b * NIN + cb * IPB + i) * DIN + k4);
        x_lds[(i * 32 + b) * 10 + (k4 >> 1)]     = pack_bf2(xv.x, xv.y);
        x_lds[(i * 32 + b) * 10 + (k4 >> 1) + 1] = pack_bf2(xv.z, xv.w);
    }
    __syncthreads();

    f32x16 sacc[4];
#pragma unroll
    for (int jj = 0; jj < 4; ++jj) sacc[jj] = (f32x16)0.0f;

#pragma unroll 1
    for (int i = 0; i < IPB; ++i) {
        const size_t wbase = (size_t)(cb * IPB + i) * WI;
        bf16x8 bfr;
        {
            uint32_t uu[4];
            const uint32_t* xp = &x_lds[(i * 32 + bl) * 10 + h * 4];
            uu[0] = xp[0]; uu[1] = xp[1]; uu[2] = xp[2]; uu[3] = xp[3];
            __builtin_memcpy(&bfr, uu, 16);
        }
#pragma unroll
        for (int jj = 0; jj < 4; ++jj) {
            const int j = j0 + jj;
            const size_t eoff = wbase + (size_t)(j * 32 + bl) * 16 + h * 8;
            const float4* wp = (const float4*)(Wf + eoff);
            const float4 a4 = wp[0], b4 = wp[1];
            uint32_t uu[4];
            uu[0] = pack_bf2(a4.x, a4.y); uu[1] = pack_bf2(a4.z, a4.w);
            uu[2] = pack_bf2(b4.x, b4.y); uu[3] = pack_bf2(b4.z, b4.w);
            bf16x8 afr; __builtin_memcpy(&afr, uu, 16);
            uint4 st; st.x = uu[0]; st.y = uu[1]; st.z = uu[2]; st.w = uu[3];
            *(uint4*)(WhOut + (eoff >> 1)) = st;
            sacc[jj] = __builtin_amdgcn_mfma_f32_32x32x16_bf16(afr, bfr, sacc[jj], 0, 0, 0);
        }
    }

#pragma unroll
    for (int jj = 0; jj < 4; ++jj) {
        const int j = j0 + jj;
#pragma unroll
        for (int r = 0; r < 16; ++r) {
            const int d = (r & 3) + 8 * (r >> 2) + 4 * h;
            s_partial[(size_t)cb * (2048 * 32) + (size_t)(j * 32 + d) * 32 + bl] =
                f2bf(sacc[jj][r] * (1.0f / 64.0f));
        }
    }
}

// ---------------- IT passes: i-paired phases, v in LDS ----------------
template <int IT>
__global__ __launch_bounds__(1024, 4) void caps_it(
    const float* __restrict__ x, const uint16_t* __restrict__ Wh,
    const float* __restrict__ v_prev, const float* __restrict__ blog_in,
    float* __restrict__ blog_out, uint16_t* __restrict__ s_partial)
{
    extern __shared__ char smem[];
    uint32_t* v_lds = (uint32_t*)(smem + VOFF);    // [64j*16dp][33b] h2
    float*    c_lds = (float*)(smem + COFF);       // [2][64][33]
    uint32_t* x_lds = (uint32_t*)(smem + XOFF);    // [8i*32b][10]

    const int cb = blockIdx.x;
    const int t  = threadIdx.x;
    const int w  = t >> 6, l = t & 63;
    const int bl = l & 31, h = l >> 5;
    const int j0 = w * 4;

    // ---- stage x -> bf16 pairs ----
    {
        const int b = t >> 5, i = (t >> 2) & 7, k4 = (t & 3) * 4;
        const float4 xv = *(const float4*)(x + ((size_t)b * NIN + cb * IPB + i) * DIN + k4);
        x_lds[(i * 32 + b) * 10 + (k4 >> 1)]     = pack_bf2(xv.x, xv.y);
        x_lds[(i * 32 + b) * 10 + (k4 >> 1) + 1] = pack_bf2(xv.z, xv.w);
    }
    // ---- stage v -> f16 pairs [j][dp][33+b] ----
#pragma unroll 4
    for (int rep = 0; rep < 32; ++rep) {
        const int idx = rep * 1024 + t;
        const int b = idx >> 10, j = (idx >> 4) & 63, dp = idx & 15;
        const float2 vv = *(const float2*)(v_prev + ((size_t)b * NOUT + j) * DOUT + dp * 2);
        v_lds[(j * 16 + dp) * 33 + b] = pack_h2(vv.x, vv.y);
    }
    __syncthreads();

    f32x16 sacc[4];
#pragma unroll
    for (int jj = 0; jj < 4; ++jj) sacc[jj] = (f32x16)0.0f;

    constexpr int base_dp[8] = {0, 1, 4, 5, 8, 9, 12, 13};

#pragma unroll 1
    for (int ip = 0; ip < IPB / 2; ++ip) {
        const int i0 = ip * 2;

        // x pairs for both i's of this pair (b = bl)
        uint32_t xu[2][4];
#pragma unroll
        for (int iq = 0; iq < 2; ++iq) {
            const uint32_t* xp = &x_lds[((i0 + iq) * 32 + bl) * 10 + h * 4];
            xu[iq][0] = xp[0]; xu[iq][1] = xp[1]; xu[iq][2] = xp[2]; xu[iq][3] = xp[3];
        }

        // ===== PHASE A: logits for i0, i0+1 (two independent load/MFMA chains) =====
#pragma unroll
        for (int iq = 0; iq < 2; ++iq) {
            const size_t wbase = (size_t)(cb * IPB + i0 + iq) * WI;
            bf16x8 bfr; __builtin_memcpy(&bfr, xu[iq], 16);
#pragma unroll
            for (int jj = 0; jj < 4; ++jj) {
                const int j = j0 + jj;
                const bf16x8 afr = *(const bf16x8*)(Wh + wbase + (size_t)(j * 32 + bl) * 16 + h * 8);
                const f32x16 D = __builtin_amdgcn_mfma_f32_32x32x16_bf16(afr, bfr, (f32x16)0.0f, 0, 0, 0);
                float acc = 0.f;
#pragma unroll
                for (int rp = 0; rp < 8; ++rp) {
                    const int dp = base_dp[rp] + 2 * h;
                    h2 dpk; dpk.x = (_Float16)D[2 * rp]; dpk.y = (_Float16)D[2 * rp + 1];
                    acc = __builtin_amdgcn_fdot2(dpk, as_h2(v_lds[(j * 16 + dp) * 33 + bl]), acc, false);
                }
                acc += __shfl_xor(acc, 32);       // combine d-halves
                if (h == 0) c_lds[iq * CSTRIDE + j * 33 + bl] = acc;
            }
        }
        __syncthreads();   // logits for the pair visible

        // ===== PHASE B: softmax over j — 64 (iq,b) rows, 4 per wave =====
#pragma unroll
        for (int rr = 0; rr < 4; ++rr) {
            const int row = w * 4 + rr;
            const int iq = row >> 5, b = row & 31;
            const int ig = cb * IPB + i0 + iq;
            float bv = c_lds[iq * CSTRIDE + l * 33 + b];
            if (IT == 2) bv += blog_in[((size_t)b * NIN + ig) * NOUT + l];
            if (IT == 1) blog_out[((size_t)b * NIN + ig) * NOUT + l] = bv;
            float m = bv;
#pragma unroll
            for (int o = 32; o; o >>= 1) m = fmaxf(m, __shfl_xor(m, o));
            const float e = __expf(bv - m);
            float s = e;
#pragma unroll
            for (int o = 32; o; o >>= 1) s += __shfl_xor(s, o);
            c_lds[iq * CSTRIDE + l * 33 + b] = e / s;
        }
        __syncthreads();   // couplings visible

        // ===== PHASE C: accumulate via c-scaled B-operand (W re-read is L2-hot) =====
#pragma unroll
        for (int iq = 0; iq < 2; ++iq) {
            const size_t wbase = (size_t)(cb * IPB + i0 + iq) * WI;
#pragma unroll
            for (int jj = 0; jj < 4; ++jj) {
                const int j = j0 + jj;
                const float cv = c_lds[iq * CSTRIDE + j * 33 + bl];
                uint32_t cu[4];
#pragma unroll
                for (int q = 0; q < 4; ++q)
                    cu[q] = pack_bf2(bflo(xu[iq][q]) * cv, bfhi(xu[iq][q]) * cv);
                bf16x8 cxf; __builtin_memcpy(&cxf, cu, 16);
                const bf16x8 afr = *(const bf16x8*)(Wh + wbase + (size_t)(j * 32 + bl) * 16 + h * 8);
                sacc[jj] = __builtin_amdgcn_mfma_f32_32x32x16_bf16(afr, cxf, sacc[jj], 0, 0, 0);
            }
        }
        __syncthreads();   // protect c_lds before next pair's phase A
    }

    // ---- store partials: spart[cb][jd][b] bf16 ----
#pragma unroll
    for (int jj = 0; jj < 4; ++jj) {
        const int j = j0 + jj;
#pragma unroll
        for (int r = 0; r < 16; ++r) {
            const int d = (r & 3) + 8 * (r >> 2) + 4 * h;
            s_partial[(size_t)cb * (2048 * 32) + (size_t)(j * 32 + d) * 32 + bl] =
                f2bf(sacc[jj][r]);
        }
    }
}

// ---------------- reduce over cb + bias + squash ----------------
__global__ __launch_bounds__(256) void caps_squash(
    const uint16_t* __restrict__ sp, const float* __restrict__ bias,
    float* __restrict__ vout)
{
    const int j  = blockIdx.x >> 2;
    const int bq = blockIdx.x & 3;
    const int t  = threadIdx.x;
    const int d  = t >> 3;
    const int blq = t & 7;
    const int b  = bq * 8 + blq;

    const uint16_t* p = sp + (size_t)(j * 32 + d) * 32 + b;
    float s0 = 0.f, s1 = 0.f, s2 = 0.f, s3 = 0.f;
#pragma unroll 4
    for (int c = 0; c < NCB; c += 4) {
        s0 += bf2f(p[(size_t)(c + 0) * (2048 * 32)]);
        s1 += bf2f(p[(size_t)(c + 1) * (2048 * 32)]);
        s2 += bf2f(p[(size_t)(c + 2) * (2048 * 32)]);
        s3 += bf2f(p[(size_t)(c + 3) * (2048 * 32)]);
    }
    const float sv = ((s0 + s1) + (s2 + s3)) + bias[j * DOUT + d];

    float sq = sv * sv;
    sq += __shfl_xor(sq, 8);
    sq += __shfl_xor(sq, 16);
    sq += __shfl_xor(sq, 32);

    __shared__ float sh[4][8];
    if ((t & 63) < 8) sh[t >> 6][t & 7] = sq;
    __syncthreads();
    const float tot = sh[0][blq] + sh[1][blq] + sh[2][blq] + sh[3][blq];
    const float scale = (tot / (1.0f + tot)) * rsqrtf(tot + 1e-9f);
    vout[(size_t)b * (NOUT * DOUT) + j * DOUT + d] = scale * sv;
}

extern "C" void kernel_launch(void* const* d_in, const int* in_sizes, int n_in,
                              void* d_out, int out_size, void* d_ws, size_t ws_size,
                              hipStream_t stream) {
    const float* x    = (const float*)d_in[0];
    const float* W    = (const float*)d_in[1];
    const float* bias = (const float*)d_in[2];
    float* out = (float*)d_out;

    // ws: Wh 134.22MB | blog 16.78MB | spart(bf16) 33.55MB | vbuf 0.26MB = 184.8MB
    char* base = (char*)d_ws;
    uint32_t* Wh    = (uint32_t*)base;
    float*    blog  = (float*)(base + WELEM * 2);
    uint16_t* spart = (uint16_t*)(base + WELEM * 2 + (size_t)CB * NIN * NOUT * 4);
    float*    vbuf  = (float*)(base + WELEM * 2 + (size_t)CB * NIN * NOUT * 4
                               + (size_t)NCB * 2048 * 32 * 2);
    (void)ws_size;

    hipFuncSetAttribute(reinterpret_cast<const void*>(caps_pass0),
                        hipFuncAttributeMaxDynamicSharedMemorySize, SMEM_P0);
    hipFuncSetAttribute(reinterpret_cast<const void*>(caps_it<1>),
                        hipFuncAttributeMaxDynamicSharedMemorySize, SMEM_IT);
    hipFuncSetAttribute(reinterpret_cast<const void*>(caps_it<2>),
                        hipFuncAttributeMaxDynamicSharedMemorySize, SMEM_IT);

    caps_pass0<<<NCB, 1024, SMEM_P0, stream>>>(x, W, (uint32_t*)Wh, spart);
    caps_squash<<<NOUT * 4, 256, 0, stream>>>(spart, bias, vbuf);

    caps_it<1><<<NCB, 1024, SMEM_IT, stream>>>(x, (const uint16_t*)Wh, vbuf, nullptr, blog, spart);
    caps_squash<<<NOUT * 4, 256, 0, stream>>>(spart, bias, vbuf);

    caps_it<2><<<NCB, 1024, SMEM_IT, stream>>>(x, (const uint16_t*)Wh, vbuf, blog, nullptr, spart);
    caps_squash<<<NOUT * 4, 256, 0, stream>>>(spart, bias, out);
}

// Round 15
// 273.278 us; speedup vs baseline: 1.3675x; 1.1696x over previous
//
#include <hip/hip_runtime.h>
#include <hip/hip_bf16.h>
#include <stdint.h>

// Capsule routing, f32 in/out. B=32, Nin=2048, Din=16, Nout=64, Dout=32, 3 iters.
// Round 15: R11 skeleton EXACTLY (per-i 3-barrier phases, v in LDS, 1024 thr,
// VGPR-safe) + u_hat REGISTER-CARRY: phase A saves the packed-f16 u_hat pairs
// it already builds for the logit fdot2 (Dp[4][8], 32 VGPR); phase C becomes
// register-only (c * u_hat -> sacc) -- no W re-read, no second MFMA sweep.
// IT pass W traffic halves (268 -> 134 MB). Pass0/squash unchanged from R11.

#define CB    32
#define NIN   2048
#define DIN   16
#define NOUT  64
#define DOUT  32
#define IPB   8
#define NCB   (NIN / IPB)            // 256 blocks, 1/CU
#define WI    (NOUT * DOUT * DIN)    // 32768 elements per i
#define WELEM ((size_t)NIN * WI)

typedef __attribute__((ext_vector_type(8)))  short bf16x8;
typedef __attribute__((ext_vector_type(16))) float f32x16;
typedef _Float16 h2 __attribute__((ext_vector_type(2)));

// IT LDS: v [64j*16dp][33b] u32 = 135168 | c [64][33] f32 = 8448 | x [256][10] u32 = 10240
#define VOFF 0
#define COFF 135168
#define XOFF_IT 143616
#define SMEM_IT  153856
#define SMEM_P0  10240

static __device__ __forceinline__ uint32_t pack_bf2(float a, float b) {
    __hip_bfloat162 hh = __float22bfloat162_rn(make_float2(a, b));
    uint32_t u; __builtin_memcpy(&u, &hh, 4); return u;
}
static __device__ __forceinline__ uint16_t f2bf(float v) {
    return (uint16_t)(pack_bf2(v, 0.f) & 0xffffu);
}
static __device__ __forceinline__ float bf2f(uint16_t u) {
    uint32_t v = (uint32_t)u << 16; float f; __builtin_memcpy(&f, &v, 4); return f;
}
static __device__ __forceinline__ uint32_t pack_h2(float a, float b) {
    h2 r; r.x = (_Float16)a; r.y = (_Float16)b;
    uint32_t u; __builtin_memcpy(&u, &r, 4); return u;
}
static __device__ __forceinline__ h2 as_h2(uint32_t u) {
    h2 r; __builtin_memcpy(&r, &u, 4); return r;
}

// ---------------- Pass 0: uniform coupling; streams f32 W, emits bf16 W ----------------
// Block cb owns i in [cb*8, +8), all 32 b. 16 waves, wave w owns j in [4w, 4w+4).
// Lane: bl = l&31, h = l>>5. A-frag: W[i][j*32+bl][8h..8h+8); B-frag: x[bl][i][8h..8h+8).
__global__ __launch_bounds__(1024, 4) void caps_pass0(
    const float* __restrict__ x, const float* __restrict__ Wf,
    uint32_t* __restrict__ WhOut, uint16_t* __restrict__ s_partial)
{
    extern __shared__ char smem[];
    uint32_t* x_lds = (uint32_t*)smem;             // [8i*32b][10]

    const int cb = blockIdx.x;
    const int t  = threadIdx.x;
    const int w  = t >> 6, l = t & 63;
    const int bl = l & 31, h = l >> 5;
    const int j0 = w * 4;

    {
        const int b = t >> 5, i = (t >> 2) & 7, k4 = (t & 3) * 4;
        const float4 xv = *(const float4*)(x + ((size_t)b * NIN + cb * IPB + i) * DIN + k4);
        x_lds[(i * 32 + b) * 10 + (k4 >> 1)]     = pack_bf2(xv.x, xv.y);
        x_lds[(i * 32 + b) * 10 + (k4 >> 1) + 1] = pack_bf2(xv.z, xv.w);
    }
    __syncthreads();

    f32x16 sacc[4];
#pragma unroll
    for (int jj = 0; jj < 4; ++jj) sacc[jj] = (f32x16)0.0f;

#pragma unroll 1
    for (int i = 0; i < IPB; ++i) {
        const size_t wbase = (size_t)(cb * IPB + i) * WI;
        bf16x8 bfr;
        {
            uint32_t uu[4];
            const uint32_t* xp = &x_lds[(i * 32 + bl) * 10 + h * 4];
            uu[0] = xp[0]; uu[1] = xp[1]; uu[2] = xp[2]; uu[3] = xp[3];
            __builtin_memcpy(&bfr, uu, 16);
        }
#pragma unroll
        for (int jj = 0; jj < 4; ++jj) {
            const int j = j0 + jj;
            const size_t eoff = wbase + (size_t)(j * 32 + bl) * 16 + h * 8;
            const float4* wp = (const float4*)(Wf + eoff);
            const float4 a4 = wp[0], b4 = wp[1];
            uint32_t uu[4];
            uu[0] = pack_bf2(a4.x, a4.y); uu[1] = pack_bf2(a4.z, a4.w);
            uu[2] = pack_bf2(b4.x, b4.y); uu[3] = pack_bf2(b4.z, b4.w);
            bf16x8 afr; __builtin_memcpy(&afr, uu, 16);
            uint4 st; st.x = uu[0]; st.y = uu[1]; st.z = uu[2]; st.w = uu[3];
            *(uint4*)(WhOut + (eoff >> 1)) = st;
            sacc[jj] = __builtin_amdgcn_mfma_f32_32x32x16_bf16(afr, bfr, sacc[jj], 0, 0, 0);
        }
    }

#pragma unroll
    for (int jj = 0; jj < 4; ++jj) {
        const int j = j0 + jj;
#pragma unroll
        for (int r = 0; r < 16; ++r) {
            const int d = (r & 3) + 8 * (r >> 2) + 4 * h;
            s_partial[(size_t)cb * (2048 * 32) + (size_t)(j * 32 + d) * 32 + bl] =
                f2bf(sacc[jj][r] * (1.0f / 64.0f));
        }
    }
}

// ---------------- IT passes: per-i phases, u_hat carried in registers ----------------
template <int IT>
__global__ __launch_bounds__(1024, 4) void caps_it(
    const float* __restrict__ x, const uint16_t* __restrict__ Wh,
    const float* __restrict__ v_prev, const float* __restrict__ blog_in,
    float* __restrict__ blog_out, uint16_t* __restrict__ s_partial)
{
    extern __shared__ char smem[];
    uint32_t* v_lds = (uint32_t*)(smem + VOFF);      // [64j*16dp][33b] h2
    float*    c_lds = (float*)(smem + COFF);         // [64][33]
    uint32_t* x_lds = (uint32_t*)(smem + XOFF_IT);   // [8i*32b][10]

    const int cb = blockIdx.x;
    const int t  = threadIdx.x;
    const int w  = t >> 6, l = t & 63;
    const int bl = l & 31, h = l >> 5;
    const int j0 = w * 4;

    // ---- stage x -> bf16 pairs ----
    {
        const int b = t >> 5, i = (t >> 2) & 7, k4 = (t & 3) * 4;
        const float4 xv = *(const float4*)(x + ((size_t)b * NIN + cb * IPB + i) * DIN + k4);
        x_lds[(i * 32 + b) * 10 + (k4 >> 1)]     = pack_bf2(xv.x, xv.y);
        x_lds[(i * 32 + b) * 10 + (k4 >> 1) + 1] = pack_bf2(xv.z, xv.w);
    }
    // ---- stage v -> f16 pairs [j][dp][33+b] ----
#pragma unroll 4
    for (int rep = 0; rep < 32; ++rep) {
        const int idx = rep * 1024 + t;
        const int b = idx >> 10, j = (idx >> 4) & 63, dp = idx & 15;
        const float2 vv = *(const float2*)(v_prev + ((size_t)b * NOUT + j) * DOUT + dp * 2);
        v_lds[(j * 16 + dp) * 33 + b] = pack_h2(vv.x, vv.y);
    }
    __syncthreads();

    f32x16 sacc[4];
#pragma unroll
    for (int jj = 0; jj < 4; ++jj) sacc[jj] = (f32x16)0.0f;

    constexpr int base_dp[8] = {0, 1, 4, 5, 8, 9, 12, 13};

#pragma unroll 1
    for (int i = 0; i < IPB; ++i) {
        const int ig = cb * IPB + i;
        const size_t wbase = (size_t)ig * WI;

        bf16x8 bfr;
        {
            uint32_t uu[4];
            const uint32_t* xp = &x_lds[(i * 32 + bl) * 10 + h * 4];
            uu[0] = xp[0]; uu[1] = xp[1]; uu[2] = xp[2]; uu[3] = xp[3];
            __builtin_memcpy(&bfr, uu, 16);
        }

        // ===== PHASE A: logits for this wave's 4 j; SAVE packed-f16 u_hat =====
        uint32_t Dp[4][8];
#pragma unroll
        for (int jj = 0; jj < 4; ++jj) {
            const int j = j0 + jj;
            const bf16x8 afr = *(const bf16x8*)(Wh + wbase + (size_t)(j * 32 + bl) * 16 + h * 8);
            const f32x16 D = __builtin_amdgcn_mfma_f32_32x32x16_bf16(afr, bfr, (f32x16)0.0f, 0, 0, 0);
            float acc = 0.f;
#pragma unroll
            for (int rp = 0; rp < 8; ++rp) {
                const int dp = base_dp[rp] + 2 * h;
                const uint32_t pk = pack_h2(D[2 * rp], D[2 * rp + 1]);
                Dp[jj][rp] = pk;
                acc = __builtin_amdgcn_fdot2(as_h2(pk), as_h2(v_lds[(j * 16 + dp) * 33 + bl]), acc, false);
            }
            acc += __shfl_xor(acc, 32);       // combine d-halves
            if (h == 0) c_lds[j * 33 + bl] = acc;
        }
        __syncthreads();   // logits visible

        // ===== PHASE B: softmax over j (32 b-rows, 2 per wave) =====
#pragma unroll
        for (int rr = 0; rr < 2; ++rr) {
            const int b = w * 2 + rr;
            float bv = c_lds[l * 33 + b];
            if (IT == 2) bv += blog_in[((size_t)b * NIN + ig) * NOUT + l];
            if (IT == 1) blog_out[((size_t)b * NIN + ig) * NOUT + l] = bv;
            float m = bv;
#pragma unroll
            for (int o = 32; o; o >>= 1) m = fmaxf(m, __shfl_xor(m, o));
            const float e = __expf(bv - m);
            float s = e;
#pragma unroll
            for (int o = 32; o; o >>= 1) s += __shfl_xor(s, o);
            c_lds[l * 33 + b] = e / s;
        }
        __syncthreads();   // couplings visible

        // ===== PHASE C: register-only accumulate c * u_hat =====
#pragma unroll
        for (int jj = 0; jj < 4; ++jj) {
            const int j = j0 + jj;
            const float cv = c_lds[j * 33 + bl];
#pragma unroll
            for (int rp = 0; rp < 8; ++rp) {
                const h2 hv = as_h2(Dp[jj][rp]);
                sacc[jj][2 * rp]     += cv * (float)hv.x;
                sacc[jj][2 * rp + 1] += cv * (float)hv.y;
            }
        }
        __syncthreads();   // protect c_lds before next i's phase A
    }

    // ---- store partials: spart[cb][jd][b] bf16 ----
#pragma unroll
    for (int jj = 0; jj < 4; ++jj) {
        const int j = j0 + jj;
#pragma unroll
        for (int r = 0; r < 16; ++r) {
            const int d = (r & 3) + 8 * (r >> 2) + 4 * h;
            s_partial[(size_t)cb * (2048 * 32) + (size_t)(j * 32 + d) * 32 + bl] =
                f2bf(sacc[jj][r]);
        }
    }
}

// ---------------- reduce over cb + bias + squash ----------------
__global__ __launch_bounds__(256) void caps_squash(
    const uint16_t* __restrict__ sp, const float* __restrict__ bias,
    float* __restrict__ vout)
{
    const int j  = blockIdx.x >> 2;
    const int bq = blockIdx.x & 3;
    const int t  = threadIdx.x;
    const int d  = t >> 3;
    const int blq = t & 7;
    const int b  = bq * 8 + blq;

    const uint16_t* p = sp + (size_t)(j * 32 + d) * 32 + b;
    float s0 = 0.f, s1 = 0.f, s2 = 0.f, s3 = 0.f;
#pragma unroll 4
    for (int c = 0; c < NCB; c += 4) {
        s0 += bf2f(p[(size_t)(c + 0) * (2048 * 32)]);
        s1 += bf2f(p[(size_t)(c + 1) * (2048 * 32)]);
        s2 += bf2f(p[(size_t)(c + 2) * (2048 * 32)]);
        s3 += bf2f(p[(size_t)(c + 3) * (2048 * 32)]);
    }
    const float sv = ((s0 + s1) + (s2 + s3)) + bias[j * DOUT + d];

    float sq = sv * sv;
    sq += __shfl_xor(sq, 8);
    sq += __shfl_xor(sq, 16);
    sq += __shfl_xor(sq, 32);

    __shared__ float sh[4][8];
    if ((t & 63) < 8) sh[t >> 6][t & 7] = sq;
    __syncthreads();
    const float tot = sh[0][blq] + sh[1][blq] + sh[2][blq] + sh[3][blq];
    const float scale = (tot / (1.0f + tot)) * rsqrtf(tot + 1e-9f);
    vout[(size_t)b * (NOUT * DOUT) + j * DOUT + d] = scale * sv;
}

extern "C" void kernel_launch(void* const* d_in, const int* in_sizes, int n_in,
                              void* d_out, int out_size, void* d_ws, size_t ws_size,
                              hipStream_t stream) {
    const float* x    = (const float*)d_in[0];
    const float* W    = (const float*)d_in[1];
    const float* bias = (const float*)d_in[2];
    float* out = (float*)d_out;

    // ws: Wh 134.22MB | blog 16.78MB | spart(bf16) 33.55MB | vbuf 0.26MB = 184.8MB
    char* base = (char*)d_ws;
    uint32_t* Wh    = (uint32_t*)base;
    float*    blog  = (float*)(base + WELEM * 2);
    uint16_t* spart = (uint16_t*)(base + WELEM * 2 + (size_t)CB * NIN * NOUT * 4);
    float*    vbuf  = (float*)(base + WELEM * 2 + (size_t)CB * NIN * NOUT * 4
                               + (size_t)NCB * 2048 * 32 * 2);
    (void)ws_size;

    hipFuncSetAttribute(reinterpret_cast<const void*>(caps_pass0),
                        hipFuncAttributeMaxDynamicSharedMemorySize, SMEM_P0);
    hipFuncSetAttribute(reinterpret_cast<const void*>(caps_it<1>),
                        hipFuncAttributeMaxDynamicSharedMemorySize, SMEM_IT);
    hipFuncSetAttribute(reinterpret_cast<const void*>(caps_it<2>),
                        hipFuncAttributeMaxDynamicSharedMemorySize, SMEM_IT);

    caps_pass0<<<NCB, 1024, SMEM_P0, stream>>>(x, W, (uint32_t*)Wh, spart);
    caps_squash<<<NOUT * 4, 256, 0, stream>>>(spart, bias, vbuf);

    caps_it<1><<<NCB, 1024, SMEM_IT, stream>>>(x, (const uint16_t*)Wh, vbuf, nullptr, blog, spart);
    caps_squash<<<NOUT * 4, 256, 0, stream>>>(spart, bias, vbuf);

    caps_it<2><<<NCB, 1024, SMEM_IT, stream>>>(x, (const uint16_t*)Wh, vbuf, blog, nullptr, spart);
    caps_squash<<<NOUT * 4, 256, 0, stream>>>(spart, bias, out);
}

// Round 16
// 252.560 us; speedup vs baseline: 1.4797x; 1.0820x over previous
//
#include <hip/hip_runtime.h>
#include <hip/hip_cooperative_groups.h>
#include <hip/hip_bf16.h>
#include <stdint.h>

namespace cg = cooperative_groups;

// Capsule routing, f32 in/out. B=32, Nin=2048, Din=16, Nout=64, Dout=32, 3 iters.
// Round 16: R11 phase bodies FROZEN (fastest measured: 249us). Changes:
//  (1) whole algorithm fused into ONE cooperative kernel (256 blocks = 1/CU,
//      grid.sync between phases) -> no launch gaps, x staged once;
//  (2) c_lds double-buffer (R13-validated) -> 16 barriers/block/IT-pass not 24.
// Fallback to separate kernels if cooperative launch unsupported.

#define CB    32
#define NIN   2048
#define DIN   16
#define NOUT  64
#define DOUT  32
#define IPB   8
#define NCB   (NIN / IPB)            // 256 blocks, 1/CU
#define WI    (NOUT * DOUT * DIN)    // 32768 elements per i
#define WELEM ((size_t)NIN * WI)

typedef __attribute__((ext_vector_type(8)))  short bf16x8;
typedef __attribute__((ext_vector_type(16))) float f32x16;
typedef _Float16 h2 __attribute__((ext_vector_type(2)));

// LDS: v [64j*16dp][33b] u32 =135168 | c dbuf [2][64*33] f32 =16896 | x [256][10] u32 =10240
#define VOFF    0
#define COFF    135168
#define CSTRIDE 2112
#define XOFF    152064
#define SMEM_FUSED 162304

static __device__ __forceinline__ uint32_t pack_bf2(float a, float b) {
    __hip_bfloat162 hh = __float22bfloat162_rn(make_float2(a, b));
    uint32_t u; __builtin_memcpy(&u, &hh, 4); return u;
}
static __device__ __forceinline__ uint16_t f2bf(float v) {
    return (uint16_t)(pack_bf2(v, 0.f) & 0xffffu);
}
static __device__ __forceinline__ float bf2f(uint16_t u) {
    uint32_t v = (uint32_t)u << 16; float f; __builtin_memcpy(&f, &v, 4); return f;
}
static __device__ __forceinline__ uint32_t pack_h2(float a, float b) {
    h2 r; r.x = (_Float16)a; r.y = (_Float16)b;
    uint32_t u; __builtin_memcpy(&u, &r, 4); return u;
}
static __device__ __forceinline__ h2 as_h2(uint32_t u) {
    h2 r; __builtin_memcpy(&r, &u, 4); return r;
}

// ---------------- shared phase bodies (R11-verbatim logic) ----------------

static __device__ __forceinline__ void stage_x(const float* __restrict__ x,
                                               uint32_t* x_lds, int cb, int t) {
    const int b = t >> 5, i = (t >> 2) & 7, k4 = (t & 3) * 4;
    const float4 xv = *(const float4*)(x + ((size_t)b * NIN + cb * IPB + i) * DIN + k4);
    x_lds[(i * 32 + b) * 10 + (k4 >> 1)]     = pack_bf2(xv.x, xv.y);
    x_lds[(i * 32 + b) * 10 + (k4 >> 1) + 1] = pack_bf2(xv.z, xv.w);
}

static __device__ __forceinline__ void stage_v(const float* __restrict__ v_prev,
                                               uint32_t* v_lds, int t) {
#pragma unroll 4
    for (int rep = 0; rep < 32; ++rep) {
        const int idx = rep * 1024 + t;
        const int b = idx >> 10, j = (idx >> 4) & 63, dp = idx & 15;
        const float2 vv = *(const float2*)(v_prev + ((size_t)b * NOUT + j) * DOUT + dp * 2);
        v_lds[(j * 16 + dp) * 33 + b] = pack_h2(vv.x, vv.y);
    }
}

// Pass 0: uniform coupling; streams f32 W, emits bf16 W, accumulates sacc.
static __device__ __forceinline__ void pass0_body(
    const float* __restrict__ Wf, uint32_t* __restrict__ WhOut,
    uint16_t* __restrict__ s_partial, const uint32_t* x_lds, int cb, int t)
{
    const int w = t >> 6, l = t & 63;
    const int bl = l & 31, h = l >> 5;
    const int j0 = w * 4;

    f32x16 sacc[4];
#pragma unroll
    for (int jj = 0; jj < 4; ++jj) sacc[jj] = (f32x16)0.0f;

#pragma unroll 1
    for (int i = 0; i < IPB; ++i) {
        const size_t wbase = (size_t)(cb * IPB + i) * WI;
        bf16x8 bfr;
        {
            uint32_t uu[4];
            const uint32_t* xp = &x_lds[(i * 32 + bl) * 10 + h * 4];
            uu[0] = xp[0]; uu[1] = xp[1]; uu[2] = xp[2]; uu[3] = xp[3];
            __builtin_memcpy(&bfr, uu, 16);
        }
#pragma unroll
        for (int jj = 0; jj < 4; ++jj) {
            const int j = j0 + jj;
            const size_t eoff = wbase + (size_t)(j * 32 + bl) * 16 + h * 8;
            const float4* wp = (const float4*)(Wf + eoff);
            const float4 a4 = wp[0], b4 = wp[1];
            uint32_t uu[4];
            uu[0] = pack_bf2(a4.x, a4.y); uu[1] = pack_bf2(a4.z, a4.w);
            uu[2] = pack_bf2(b4.x, b4.y); uu[3] = pack_bf2(b4.z, b4.w);
            bf16x8 afr; __builtin_memcpy(&afr, uu, 16);
            uint4 st; st.x = uu[0]; st.y = uu[1]; st.z = uu[2]; st.w = uu[3];
            *(uint4*)(WhOut + (eoff >> 1)) = st;
            sacc[jj] = __builtin_amdgcn_mfma_f32_32x32x16_bf16(afr, bfr, sacc[jj], 0, 0, 0);
        }
    }

#pragma unroll
    for (int jj = 0; jj < 4; ++jj) {
        const int j = j0 + jj;
#pragma unroll
        for (int r = 0; r < 16; ++r) {
            const int d = (r & 3) + 8 * (r >> 2) + 4 * h;
            s_partial[(size_t)cb * (2048 * 32) + (size_t)(j * 32 + d) * 32 + bl] =
                f2bf(sacc[jj][r] * (1.0f / 64.0f));
        }
    }
}

// IT pass: per-i {A logits, bar, B softmax, bar, C accumulate} with c_lds dbuf.
template <int IT>
static __device__ __forceinline__ void it_body(
    const uint16_t* __restrict__ Wh, const float* __restrict__ blog_in,
    float* __restrict__ blog_out, uint16_t* __restrict__ s_partial,
    const uint32_t* v_lds, float* c_lds, const uint32_t* x_lds, int cb, int t)
{
    const int w = t >> 6, l = t & 63;
    const int bl = l & 31, h = l >> 5;
    const int j0 = w * 4;

    f32x16 sacc[4];
#pragma unroll
    for (int jj = 0; jj < 4; ++jj) sacc[jj] = (f32x16)0.0f;

    constexpr int base_dp[8] = {0, 1, 4, 5, 8, 9, 12, 13};

#pragma unroll 1
    for (int i = 0; i < IPB; ++i) {
        float* cp = c_lds + (i & 1) * CSTRIDE;
        const int ig = cb * IPB + i;
        const size_t wbase = (size_t)ig * WI;

        bf16x8 bfr;
        {
            uint32_t uu[4];
            const uint32_t* xp = &x_lds[(i * 32 + bl) * 10 + h * 4];
            uu[0] = xp[0]; uu[1] = xp[1]; uu[2] = xp[2]; uu[3] = xp[3];
            __builtin_memcpy(&bfr, uu, 16);
        }

        // ===== PHASE A: logits for this wave's 4 j =====
#pragma unroll
        for (int jj = 0; jj < 4; ++jj) {
            const int j = j0 + jj;
            const bf16x8 afr = *(const bf16x8*)(Wh + wbase + (size_t)(j * 32 + bl) * 16 + h * 8);
            const f32x16 D = __builtin_amdgcn_mfma_f32_32x32x16_bf16(afr, bfr, (f32x16)0.0f, 0, 0, 0);
            float acc = 0.f;
#pragma unroll
            for (int rp = 0; rp < 8; ++rp) {
                const int dp = base_dp[rp] + 2 * h;
                h2 dpk; dpk.x = (_Float16)D[2 * rp]; dpk.y = (_Float16)D[2 * rp + 1];
                acc = __builtin_amdgcn_fdot2(dpk, as_h2(v_lds[(j * 16 + dp) * 33 + bl]), acc, false);
            }
            acc += __shfl_xor(acc, 32);       // combine d-halves
            if (h == 0) cp[j * 33 + bl] = acc;
        }
        __syncthreads();   // A(i) visible

        // ===== PHASE B: softmax over j (32 b-rows, 2 per wave) =====
#pragma unroll
        for (int rr = 0; rr < 2; ++rr) {
            const int b = w * 2 + rr;
            float bv = cp[l * 33 + b];
            if (IT == 2) bv += blog_in[((size_t)b * NIN + ig) * NOUT + l];
            if (IT == 1) blog_out[((size_t)b * NIN + ig) * NOUT + l] = bv;
            float m = bv;
#pragma unroll
            for (int o = 32; o; o >>= 1) m = fmaxf(m, __shfl_xor(m, o));
            const float e = __expf(bv - m);
            float s = e;
#pragma unroll
            for (int o = 32; o; o >>= 1) s += __shfl_xor(s, o);
            cp[l * 33 + b] = e / s;
        }
        __syncthreads();   // B(i) visible

        // ===== PHASE C: re-MFMA + c-scaled accumulate (no trailing barrier:
        //        A(i+1) writes the other c_lds buffer) =====
#pragma unroll
        for (int jj = 0; jj < 4; ++jj) {
            const int j = j0 + jj;
            const bf16x8 afr = *(const bf16x8*)(Wh + wbase + (size_t)(j * 32 + bl) * 16 + h * 8);
            const f32x16 D = __builtin_amdgcn_mfma_f32_32x32x16_bf16(afr, bfr, (f32x16)0.0f, 0, 0, 0);
            const float cv = cp[j * 33 + bl];
            sacc[jj] += D * cv;
        }
    }

#pragma unroll
    for (int jj = 0; jj < 4; ++jj) {
        const int j = j0 + jj;
#pragma unroll
        for (int r = 0; r < 16; ++r) {
            const int d = (r & 3) + 8 * (r >> 2) + 4 * h;
            s_partial[(size_t)cb * (2048 * 32) + (size_t)(j * 32 + d) * 32 + bl] =
                f2bf(sacc[jj][r]);
        }
    }
}

// Squash for the fused kernel: 1024-thread-safe (t<256 active), sh in smem[0..128).
static __device__ __forceinline__ void squash_body(
    const uint16_t* __restrict__ sp, const float* __restrict__ bias,
    float* __restrict__ vout, char* smem, int cbid, int t)
{
    const int j  = cbid >> 2;
    const int bq = cbid & 3;
    const int d   = (t >> 3) & 31;
    const int blq = t & 7;
    const int b   = bq * 8 + blq;
    float sv = 0.f, sq = 0.f;
    if (t < 256) {
        const uint16_t* p = sp + (size_t)(j * 32 + d) * 32 + b;
        float s0 = 0.f, s1 = 0.f, s2 = 0.f, s3 = 0.f;
#pragma unroll 4
        for (int c = 0; c < NCB; c += 4) {
            s0 += bf2f(p[(size_t)(c + 0) * (2048 * 32)]);
            s1 += bf2f(p[(size_t)(c + 1) * (2048 * 32)]);
            s2 += bf2f(p[(size_t)(c + 2) * (2048 * 32)]);
            s3 += bf2f(p[(size_t)(c + 3) * (2048 * 32)]);
        }
        sv = ((s0 + s1) + (s2 + s3)) + bias[j * DOUT + d];
        sq = sv * sv;
        sq += __shfl_xor(sq, 8);
        sq += __shfl_xor(sq, 16);
        sq += __shfl_xor(sq, 32);
    }
    float* sh = (float*)smem;
    if (t < 256 && (t & 63) < 8) sh[(t >> 6) * 8 + (t & 7)] = sq;
    __syncthreads();
    if (t < 256) {
        const float tot = sh[0 * 8 + blq] + sh[1 * 8 + blq] + sh[2 * 8 + blq] + sh[3 * 8 + blq];
        const float scale = (tot / (1.0f + tot)) * rsqrtf(tot + 1e-9f);
        vout[(size_t)b * (NOUT * DOUT) + j * DOUT + d] = scale * sv;
    }
}

// ---------------- fused cooperative kernel ----------------
__global__ __launch_bounds__(1024, 4) void caps_fused(
    const float* __restrict__ x, const float* __restrict__ Wf,
    uint32_t* __restrict__ Wh, float* __restrict__ blog,
    uint16_t* __restrict__ spart, const float* __restrict__ bias,
    float* __restrict__ vbuf, float* __restrict__ out)
{
    cg::grid_group grid = cg::this_grid();
    extern __shared__ char smem[];
    uint32_t* v_lds = (uint32_t*)(smem + VOFF);
    float*    c_lds = (float*)(smem + COFF);
    uint32_t* x_lds = (uint32_t*)(smem + XOFF);
    const int cb = blockIdx.x;
    const int t  = threadIdx.x;

    stage_x(x, x_lds, cb, t);
    __syncthreads();

    pass0_body(Wf, Wh, spart, x_lds, cb, t);
    __threadfence();
    grid.sync();

    squash_body(spart, bias, vbuf, smem, cb, t);
    __threadfence();
    grid.sync();

    stage_v(vbuf, v_lds, t);
    __syncthreads();
    it_body<1>((const uint16_t*)Wh, nullptr, blog, spart, v_lds, c_lds, x_lds, cb, t);
    __threadfence();
    grid.sync();

    squash_body(spart, bias, vbuf, smem, cb, t);
    __threadfence();
    grid.sync();

    stage_v(vbuf, v_lds, t);
    __syncthreads();
    it_body<2>((const uint16_t*)Wh, blog, nullptr, spart, v_lds, c_lds, x_lds, cb, t);
    __threadfence();
    grid.sync();

    squash_body(spart, bias, out, smem, cb, t);
}

// ---------------- fallback kernels (separate launches) ----------------
__global__ __launch_bounds__(1024, 4) void k_pass0(
    const float* __restrict__ x, const float* __restrict__ Wf,
    uint32_t* __restrict__ Wh, uint16_t* __restrict__ spart)
{
    extern __shared__ char smem[];
    uint32_t* x_lds = (uint32_t*)(smem + XOFF);
    stage_x(x, x_lds, blockIdx.x, threadIdx.x);
    __syncthreads();
    pass0_body(Wf, Wh, spart, x_lds, blockIdx.x, threadIdx.x);
}

template <int IT>
__global__ __launch_bounds__(1024, 4) void k_it(
    const float* __restrict__ x, const uint16_t* __restrict__ Wh,
    const float* __restrict__ v_prev, const float* __restrict__ blog_in,
    float* __restrict__ blog_out, uint16_t* __restrict__ spart)
{
    extern __shared__ char smem[];
    uint32_t* v_lds = (uint32_t*)(smem + VOFF);
    float*    c_lds = (float*)(smem + COFF);
    uint32_t* x_lds = (uint32_t*)(smem + XOFF);
    stage_x(x, x_lds, blockIdx.x, threadIdx.x);
    stage_v(v_prev, v_lds, threadIdx.x);
    __syncthreads();
    it_body<IT>(Wh, blog_in, blog_out, spart, v_lds, c_lds, x_lds, blockIdx.x, threadIdx.x);
}

__global__ __launch_bounds__(256) void k_squash(
    const uint16_t* __restrict__ sp, const float* __restrict__ bias,
    float* __restrict__ vout)
{
    __shared__ char smem[128];
    squash_body(sp, bias, vout, smem, blockIdx.x, threadIdx.x);
}

extern "C" void kernel_launch(void* const* d_in, const int* in_sizes, int n_in,
                              void* d_out, int out_size, void* d_ws, size_t ws_size,
                              hipStream_t stream) {
    const float* x    = (const float*)d_in[0];
    const float* Wf   = (const float*)d_in[1];
    const float* bias = (const float*)d_in[2];
    float* out = (float*)d_out;

    // ws: Wh 134.22MB | blog 16.78MB | spart(bf16) 33.55MB | vbuf 0.26MB = 184.8MB
    char* base = (char*)d_ws;
    uint32_t* Wh    = (uint32_t*)base;
    float*    blog  = (float*)(base + WELEM * 2);
    uint16_t* spart = (uint16_t*)(base + WELEM * 2 + (size_t)CB * NIN * NOUT * 4);
    float*    vbuf  = (float*)(base + WELEM * 2 + (size_t)CB * NIN * NOUT * 4
                               + (size_t)NCB * 2048 * 32 * 2);
    (void)ws_size;

    hipFuncSetAttribute(reinterpret_cast<const void*>(caps_fused),
                        hipFuncAttributeMaxDynamicSharedMemorySize, SMEM_FUSED);
    hipFuncSetAttribute(reinterpret_cast<const void*>(k_pass0),
                        hipFuncAttributeMaxDynamicSharedMemorySize, SMEM_FUSED);
    hipFuncSetAttribute(reinterpret_cast<const void*>(k_it<1>),
                        hipFuncAttributeMaxDynamicSharedMemorySize, SMEM_FUSED);
    hipFuncSetAttribute(reinterpret_cast<const void*>(k_it<2>),
                        hipFuncAttributeMaxDynamicSharedMemorySize, SMEM_FUSED);

    // host-side capability check (no stream ops; graph-capture safe)
    int dev = 0; hipGetDevice(&dev);
    int coop = 0;
    hipDeviceGetAttribute(&coop, hipDeviceAttributeCooperativeLaunch, dev);
    int nb = 0;
    hipError_t occ = hipOccupancyMaxActiveBlocksPerMultiprocessor(
        &nb, reinterpret_cast<const void*>(caps_fused), 1024, SMEM_FUSED);

    if (coop && occ == hipSuccess && nb >= 1) {
        void* args[] = {(void*)&x, (void*)&Wf, (void*)&Wh, (void*)&blog,
                        (void*)&spart, (void*)&bias, (void*)&vbuf, (void*)&out};
        hipLaunchCooperativeKernel(reinterpret_cast<const void*>(caps_fused),
                                   dim3(NCB), dim3(1024), args, SMEM_FUSED, stream);
    } else {
        k_pass0<<<NCB, 1024, SMEM_FUSED, stream>>>(x, Wf, Wh, spart);
        k_squash<<<NOUT * 4, 256, 0, stream>>>(spart, bias, vbuf);
        k_it<1><<<NCB, 1024, SMEM_FUSED, stream>>>(x, (const uint16_t*)Wh, vbuf, nullptr, blog, spart);
        k_squash<<<NOUT * 4, 256, 0, stream>>>(spart, bias, vbuf);
        k_it<2><<<NCB, 1024, SMEM_FUSED, stream>>>(x, (const uint16_t*)Wh, vbuf, blog, nullptr, spart);
        k_squash<<<NOUT * 4, 256, 0, stream>>>(spart, bias, out);
    }
}

// Round 17
// 248.778 us; speedup vs baseline: 1.5022x; 1.0152x over previous
//
#include <hip/hip_runtime.h>
#include <hip/hip_bf16.h>
#include <stdint.h>

// Capsule routing, f32 in/out. B=32, Nin=2048, Din=16, Nout=64, Dout=32, 3 iters.
// FINAL (= Round-11 configuration, the measured optimum of this session: 249us).
// mfma_f32_32x32x16_bf16 (K=16=Din exact; M=32 d-rows of one j; N=32 = ALL
// batches -> zero cross-block W sharing). Per-i {logits -> softmax -> weighted
// accumulate} with W_i L2-hot for the phase-C re-read. Pass0 fuses the
// f32->bf16 W transcode into its mandatory f32-W sweep. 1024-thr blocks,
// v-table in LDS (f16 pairs), spart in bf16.
//
// Post-mortem summary of rejected variants (all measured slower):
//  - G=16 / 2-bg blocks (R12): 2x Wh L3 traffic.
//  - v in 32 VGPRs/lane (R13): VGPR wall -> scratch spill.
//  - i-pairing, 2x phase-A depth (R14): doubled A-transients -> spill.
//  - u_hat f16 register-carry (R15): +32 persistent VGPR, serial cvt chain.
//  - cooperative whole-net fusion (R16): VGPR clamp 64 -> 318MB scratch.

#define CB    32
#define NIN   2048
#define DIN   16
#define NOUT  64
#define DOUT  32
#define IPB   8
#define NCB   (NIN / IPB)            // 256 blocks, 1/CU
#define WI    (NOUT * DOUT * DIN)    // 32768 elements per i
#define WELEM ((size_t)NIN * WI)

typedef __attribute__((ext_vector_type(8)))  short bf16x8;
typedef __attribute__((ext_vector_type(16))) float f32x16;
typedef _Float16 h2 __attribute__((ext_vector_type(2)));

// LDS layout (bytes): IT>0: [v 135168][c 8448][x 10240] = 153856; IT0: [x 10240]
#define VOFF 0
#define COFF 135168
#define XOFF_IT 143616
#define SMEM_IT  153856
#define SMEM_P0  10240

static __device__ __forceinline__ uint32_t pack_bf2(float a, float b) {
    __hip_bfloat162 hh = __float22bfloat162_rn(make_float2(a, b));
    uint32_t u; __builtin_memcpy(&u, &hh, 4); return u;
}
static __device__ __forceinline__ uint16_t f2bf(float v) {
    return (uint16_t)(pack_bf2(v, 0.f) & 0xffffu);
}
static __device__ __forceinline__ float bf2f(uint16_t u) {
    uint32_t v = (uint32_t)u << 16; float f; __builtin_memcpy(&f, &v, 4); return f;
}
static __device__ __forceinline__ uint32_t pack_h2(float a, float b) {
    h2 r; r.x = (_Float16)a; r.y = (_Float16)b;
    uint32_t u; __builtin_memcpy(&u, &r, 4); return u;
}
static __device__ __forceinline__ h2 as_h2(uint32_t u) {
    h2 r; __builtin_memcpy(&r, &u, 4); return r;
}

// ---------------- routing pass ----------------
// Block cb owns i in [cb*8, cb*8+8), ALL 32 batches. 16 waves; wave w owns
// j in [w*4, w*4+4). Lane: bl = l&31 (= b for B/D cols, = jd-row for A), h = l>>5.
// A-frag: W[i][j*32+bl][k=8h..8h+8)   B-frag: x[bl][i][k=8h..8h+8)
// D (verified C/D layout): col b = l&31, row d = (reg&3)+8*(reg>>2)+4h.
template <int IT>
__global__ __launch_bounds__(1024, 4) void caps_pass(
    const float* __restrict__ x, const void* __restrict__ Wv,
    uint32_t* __restrict__ WhOut,
    const float* __restrict__ v_prev, const float* __restrict__ blog_in,
    float* __restrict__ blog_out, uint16_t* __restrict__ s_partial)
{
    extern __shared__ char smem[];
    uint32_t* v_lds = (uint32_t*)(smem + VOFF);                  // [64j*16dp][33b] h2
    float*    c_lds = (float*)(smem + COFF);                     // [64j][33b]
    uint32_t* x_lds = (uint32_t*)(smem + (IT > 0 ? XOFF_IT : 0)); // [8i*32b][10] k-pairs

    const int cb = blockIdx.x;
    const int t  = threadIdx.x;
    const int w  = t >> 6, l = t & 63;
    const int bl = l & 31, h = l >> 5;
    const int j0 = w * 4;

    // ---- stage x -> bf16 pairs (coalesced: consecutive t = consecutive k4,i) ----
    {
        const int b = t >> 5, i = (t >> 2) & 7, k4 = (t & 3) * 4;
        const float4 xv = *(const float4*)(x + ((size_t)b * NIN + cb * IPB + i) * DIN + k4);
        x_lds[(i * 32 + b) * 10 + (k4 >> 1)]     = pack_bf2(xv.x, xv.y);
        x_lds[(i * 32 + b) * 10 + (k4 >> 1) + 1] = pack_bf2(xv.z, xv.w);
    }
    if (IT > 0) {
        // ---- stage v -> f16 pairs [j][dp][33+b] (coalesced reads, conflict-free writes) ----
#pragma unroll 4
        for (int rep = 0; rep < 32; ++rep) {
            const int idx = rep * 1024 + t;
            const int b = idx >> 10, j = (idx >> 4) & 63, dp = idx & 15;
            const float2 vv = *(const float2*)(v_prev + ((size_t)b * NOUT + j) * DOUT + dp * 2);
            v_lds[(j * 16 + dp) * 33 + b] = pack_h2(vv.x, vv.y);
        }
    }
    __syncthreads();

    f32x16 sacc[4];
#pragma unroll
    for (int jj = 0; jj < 4; ++jj) sacc[jj] = (f32x16)0.0f;

    const uint16_t* Wb = (const uint16_t*)Wv;
    const float*    Wf = (const float*)Wv;
    constexpr int base_dp[8] = {0, 1, 4, 5, 8, 9, 12, 13};

#pragma unroll 1
    for (int i = 0; i < IPB; ++i) {
        const int ig = cb * IPB + i;
        const size_t wbase = (size_t)ig * WI;

        // B-frag (reused across j): x[bl][i][8h..8h+8)
        bf16x8 bfr;
        {
            uint32_t uu[4];
            const uint32_t* xp = &x_lds[(i * 32 + bl) * 10 + h * 4];
            uu[0] = xp[0]; uu[1] = xp[1]; uu[2] = xp[2]; uu[3] = xp[3];
            __builtin_memcpy(&bfr, uu, 16);
        }

        if (IT > 0) {
            // ===== PHASE A: logits for this wave's 4 j =====
#pragma unroll
            for (int jj = 0; jj < 4; ++jj) {
                const int j = j0 + jj;
                const bf16x8 afr = *(const bf16x8*)(Wb + wbase + (size_t)(j * 32 + bl) * 16 + h * 8);
                const f32x16 D = __builtin_amdgcn_mfma_f32_32x32x16_bf16(afr, bfr, (f32x16)0.0f, 0, 0, 0);
                float acc = 0.f;
#pragma unroll
                for (int rp = 0; rp < 8; ++rp) {
                    const int dp = base_dp[rp] + 2 * h;
                    h2 dpk; dpk.x = (_Float16)D[2 * rp]; dpk.y = (_Float16)D[2 * rp + 1];
                    acc = __builtin_amdgcn_fdot2(dpk, as_h2(v_lds[(j * 16 + dp) * 33 + bl]), acc, false);
                }
                acc += __shfl_xor(acc, 32);       // combine d-halves
                if (h == 0) c_lds[j * 33 + bl] = acc;
            }
            __syncthreads();

            // ===== PHASE B: softmax over j (32 b-rows, 2 per wave) =====
#pragma unroll
            for (int rr = 0; rr < 2; ++rr) {
                const int b = w * 2 + rr;
                float bv = c_lds[l * 33 + b];
                if (IT == 2) bv += blog_in[((size_t)b * NIN + ig) * NOUT + l];
                if (IT == 1) blog_out[((size_t)b * NIN + ig) * NOUT + l] = bv;
                float m = bv;
#pragma unroll
                for (int o = 32; o; o >>= 1) m = fmaxf(m, __shfl_xor(m, o));
                const float e = __expf(bv - m);
                float s = e;
#pragma unroll
                for (int o = 32; o; o >>= 1) s += __shfl_xor(s, o);
                c_lds[l * 33 + b] = e / s;
            }
            __syncthreads();
        }

        // ===== PHASE C: accumulate =====
#pragma unroll
        for (int jj = 0; jj < 4; ++jj) {
            const int j = j0 + jj;
            if (IT == 0) {
                // f32 W -> bf16 frag + emit Wh (fused transcode)
                const float4* wp = (const float4*)(Wf + wbase + (size_t)(j * 32 + bl) * 16 + h * 8);
                const float4 a4 = wp[0], b4 = wp[1];
                uint32_t uu[4];
                uu[0] = pack_bf2(a4.x, a4.y); uu[1] = pack_bf2(a4.z, a4.w);
                uu[2] = pack_bf2(b4.x, b4.y); uu[3] = pack_bf2(b4.z, b4.w);
                bf16x8 afr; __builtin_memcpy(&afr, uu, 16);
                uint4 st; st.x = uu[0]; st.y = uu[1]; st.z = uu[2]; st.w = uu[3];
                *(uint4*)(WhOut + ((wbase + (size_t)(j * 32 + bl) * 16 + h * 8) >> 1)) = st;
                sacc[jj] = __builtin_amdgcn_mfma_f32_32x32x16_bf16(afr, bfr, sacc[jj], 0, 0, 0);
            } else {
                const bf16x8 afr = *(const bf16x8*)(Wb + wbase + (size_t)(j * 32 + bl) * 16 + h * 8);
                const f32x16 D = __builtin_amdgcn_mfma_f32_32x32x16_bf16(afr, bfr, (f32x16)0.0f, 0, 0, 0);
                const float cv = c_lds[j * 33 + bl];      // c[b,i,j]: d-invariant
                sacc[jj] += D * cv;
            }
        }
        if (IT > 0) __syncthreads();   // protect c_lds before next i's phase A
    }

    // ---- store partials: spart[cb][jd][b] bf16 ----
    const float cscale = (IT == 0) ? (1.0f / 64.0f) : 1.0f;
#pragma unroll
    for (int jj = 0; jj < 4; ++jj) {
        const int j = j0 + jj;
#pragma unroll
        for (int r = 0; r < 16; ++r) {
            const int d = (r & 3) + 8 * (r >> 2) + 4 * h;
            s_partial[(size_t)cb * (2048 * 32) + (size_t)(j * 32 + d) * 32 + bl] =
                f2bf(sacc[jj][r] * cscale);
        }
    }
}

// ---------------- reduce over cb + bias + squash ----------------
// grid 256 = (j, b-octet); 256 thr: d = t>>3, blq = t&7.
__global__ __launch_bounds__(256) void caps_squash(
    const uint16_t* __restrict__ sp, const float* __restrict__ bias,
    float* __restrict__ vout)
{
    const int j  = blockIdx.x >> 2;
    const int bq = blockIdx.x & 3;
    const int t  = threadIdx.x;
    const int d  = t >> 3;
    const int blq = t & 7;
    const int b  = bq * 8 + blq;

    const uint16_t* p = sp + (size_t)(j * 32 + d) * 32 + b;
    float s0 = 0.f, s1 = 0.f, s2 = 0.f, s3 = 0.f;
#pragma unroll 4
    for (int c = 0; c < NCB; c += 4) {
        s0 += bf2f(p[(size_t)(c + 0) * (2048 * 32)]);
        s1 += bf2f(p[(size_t)(c + 1) * (2048 * 32)]);
        s2 += bf2f(p[(size_t)(c + 2) * (2048 * 32)]);
        s3 += bf2f(p[(size_t)(c + 3) * (2048 * 32)]);
    }
    const float sv = ((s0 + s1) + (s2 + s3)) + bias[j * DOUT + d];

    float sq = sv * sv;
    sq += __shfl_xor(sq, 8);    // d within-wave octet reduce (same blq)
    sq += __shfl_xor(sq, 16);
    sq += __shfl_xor(sq, 32);

    __shared__ float sh[4][8];
    if ((t & 63) < 8) sh[t >> 6][t & 7] = sq;
    __syncthreads();
    const float tot = sh[0][blq] + sh[1][blq] + sh[2][blq] + sh[3][blq];
    const float scale = (tot / (1.0f + tot)) * rsqrtf(tot + 1e-9f);
    vout[(size_t)b * (NOUT * DOUT) + j * DOUT + d] = scale * sv;
}

extern "C" void kernel_launch(void* const* d_in, const int* in_sizes, int n_in,
                              void* d_out, int out_size, void* d_ws, size_t ws_size,
                              hipStream_t stream) {
    const float* x    = (const float*)d_in[0];
    const float* W    = (const float*)d_in[1];
    const float* bias = (const float*)d_in[2];
    float* out = (float*)d_out;

    // ws: Wh 134.22MB | blog 16.78MB | spart(bf16) 33.55MB | vbuf 0.26MB = 184.8MB
    char* base = (char*)d_ws;
    uint32_t* Wh    = (uint32_t*)base;
    float*    blog  = (float*)(base + WELEM * 2);
    uint16_t* spart = (uint16_t*)(base + WELEM * 2 + (size_t)CB * NIN * NOUT * 4);
    float*    vbuf  = (float*)(base + WELEM * 2 + (size_t)CB * NIN * NOUT * 4
                               + (size_t)NCB * 2048 * 32 * 2);
    (void)ws_size;

    hipFuncSetAttribute(reinterpret_cast<const void*>(caps_pass<0>),
                        hipFuncAttributeMaxDynamicSharedMemorySize, SMEM_P0);
    hipFuncSetAttribute(reinterpret_cast<const void*>(caps_pass<1>),
                        hipFuncAttributeMaxDynamicSharedMemorySize, SMEM_IT);
    hipFuncSetAttribute(reinterpret_cast<const void*>(caps_pass<2>),
                        hipFuncAttributeMaxDynamicSharedMemorySize, SMEM_IT);

    caps_pass<0><<<NCB, 1024, SMEM_P0, stream>>>(x, W, Wh, nullptr, nullptr, nullptr, spart);
    caps_squash<<<NOUT * 4, 256, 0, stream>>>(spart, bias, vbuf);

    caps_pass<1><<<NCB, 1024, SMEM_IT, stream>>>(x, Wh, nullptr, vbuf, nullptr, blog, spart);
    caps_squash<<<NOUT * 4, 256, 0, stream>>>(spart, bias, vbuf);

    caps_pass<2><<<NCB, 1024, SMEM_IT, stream>>>(x, Wh, nullptr, vbuf, blog, nullptr, spart);
    caps_squash<<<NOUT * 4, 256, 0, stream>>>(spart, bias, out);
}

// Round 18
// 246.873 us; speedup vs baseline: 1.5138x; 1.0077x over previous
//
#include <hip/hip_runtime.h>
#include <hip/hip_bf16.h>
#include <stdint.h>

// Capsule routing, f32 in/out. B=32, Nin=2048, Din=16, Nout=64, Dout=32, 3 iters.
// Round 18: R11/R17 IT passes + squash FROZEN (byte-identical; measured optimum).
// Only change: pass0 split by j-half -> 512 blocks x 512 threads, 2 blocks/CU
// ((512,2) = 128-VGPR cap, ~90 live regs). Pass0 has NO softmax => no cross-j
// coupling => the j-split is exact; W/Wh slices are disjoint across blocks.
// Doubles HBM-stream parallelism for the dominant compulsory 436MB sweep.

#define CB    32
#define NIN   2048
#define DIN   16
#define NOUT  64
#define DOUT  32
#define IPB   8
#define NCB   (NIN / IPB)            // 256
#define WI    (NOUT * DOUT * DIN)    // 32768 elements per i
#define WELEM ((size_t)NIN * WI)

typedef __attribute__((ext_vector_type(8)))  short bf16x8;
typedef __attribute__((ext_vector_type(16))) float f32x16;
typedef _Float16 h2 __attribute__((ext_vector_type(2)));

// IT LDS layout (bytes): [v 135168][c 8448][x 10240] = 153856
#define VOFF 0
#define COFF 135168
#define XOFF_IT 143616
#define SMEM_IT  153856

static __device__ __forceinline__ uint32_t pack_bf2(float a, float b) {
    __hip_bfloat162 hh = __float22bfloat162_rn(make_float2(a, b));
    uint32_t u; __builtin_memcpy(&u, &hh, 4); return u;
}
static __device__ __forceinline__ uint16_t f2bf(float v) {
    return (uint16_t)(pack_bf2(v, 0.f) & 0xffffu);
}
static __device__ __forceinline__ float bf2f(uint16_t u) {
    uint32_t v = (uint32_t)u << 16; float f; __builtin_memcpy(&f, &v, 4); return f;
}
static __device__ __forceinline__ uint32_t pack_h2(float a, float b) {
    h2 r; r.x = (_Float16)a; r.y = (_Float16)b;
    uint32_t u; __builtin_memcpy(&u, &r, 4); return u;
}
static __device__ __forceinline__ h2 as_h2(uint32_t u) {
    h2 r; __builtin_memcpy(&r, &u, 4); return r;
}

// ---------------- Pass 0: uniform coupling; j-half blocks; fused f32->bf16 transcode ----------------
// Block p: cb = p>>1, j-half = p&1. 8 waves; wave w owns j in [jh*32 + 4w, +4).
// Lane: bl = l&31, h = l>>5. A-frag: W[i][j*32+bl][8h..8h+8); B-frag: x[bl][i][8h..8h+8).
__global__ __launch_bounds__(512, 2) void caps_pass0(
    const float* __restrict__ x, const float* __restrict__ Wf,
    uint32_t* __restrict__ WhOut, uint16_t* __restrict__ s_partial)
{
    __shared__ uint32_t x_lds[IPB * 32 * 10];      // 10240 B

    const int p  = blockIdx.x;                     // 512 blocks
    const int cb = p >> 1, jh = p & 1;
    const int t  = threadIdx.x;
    const int w  = t >> 6, l = t & 63;
    const int bl = l & 31, h = l >> 5;
    const int j0 = jh * 32 + w * 4;

    // stage x -> bf16 pairs (2 float4 per thread; same mapping as R11)
#pragma unroll
    for (int rep = 0; rep < 2; ++rep) {
        const int q = t + rep * 512;               // 0..1023
        const int b = q >> 5, i = (q >> 2) & 7, k4 = (q & 3) * 4;
        const float4 xv = *(const float4*)(x + ((size_t)b * NIN + cb * IPB + i) * DIN + k4);
        x_lds[(i * 32 + b) * 10 + (k4 >> 1)]     = pack_bf2(xv.x, xv.y);
        x_lds[(i * 32 + b) * 10 + (k4 >> 1) + 1] = pack_bf2(xv.z, xv.w);
    }
    __syncthreads();

    f32x16 sacc[4];
#pragma unroll
    for (int jj = 0; jj < 4; ++jj) sacc[jj] = (f32x16)0.0f;

#pragma unroll 1
    for (int i = 0; i < IPB; ++i) {
        const size_t wbase = (size_t)(cb * IPB + i) * WI;
        bf16x8 bfr;
        {
            uint32_t uu[4];
            const uint32_t* xp = &x_lds[(i * 32 + bl) * 10 + h * 4];
            uu[0] = xp[0]; uu[1] = xp[1]; uu[2] = xp[2]; uu[3] = xp[3];
            __builtin_memcpy(&bfr, uu, 16);
        }
#pragma unroll
        for (int jj = 0; jj < 4; ++jj) {
            const int j = j0 + jj;
            const size_t eoff = wbase + (size_t)(j * 32 + bl) * 16 + h * 8;
            const float4* wp = (const float4*)(Wf + eoff);
            const float4 a4 = wp[0], b4 = wp[1];
            uint32_t uu[4];
            uu[0] = pack_bf2(a4.x, a4.y); uu[1] = pack_bf2(a4.z, a4.w);
            uu[2] = pack_bf2(b4.x, b4.y); uu[3] = pack_bf2(b4.z, b4.w);
            bf16x8 afr; __builtin_memcpy(&afr, uu, 16);
            uint4 st; st.x = uu[0]; st.y = uu[1]; st.z = uu[2]; st.w = uu[3];
            *(uint4*)(WhOut + (eoff >> 1)) = st;
            sacc[jj] = __builtin_amdgcn_mfma_f32_32x32x16_bf16(afr, bfr, sacc[jj], 0, 0, 0);
        }
    }

#pragma unroll
    for (int jj = 0; jj < 4; ++jj) {
        const int j = j0 + jj;
#pragma unroll
        for (int r = 0; r < 16; ++r) {
            const int d = (r & 3) + 8 * (r >> 2) + 4 * h;
            s_partial[(size_t)cb * (2048 * 32) + (size_t)(j * 32 + d) * 32 + bl] =
                f2bf(sacc[jj][r] * (1.0f / 64.0f));
        }
    }
}

// ---------------- IT passes: R11/R17 byte-identical ----------------
template <int IT>
__global__ __launch_bounds__(1024, 4) void caps_it(
    const float* __restrict__ x, const uint16_t* __restrict__ Wb,
    const float* __restrict__ v_prev, const float* __restrict__ blog_in,
    float* __restrict__ blog_out, uint16_t* __restrict__ s_partial)
{
    extern __shared__ char smem[];
    uint32_t* v_lds = (uint32_t*)(smem + VOFF);      // [64j*16dp][33b] h2
    float*    c_lds = (float*)(smem + COFF);         // [64j][33b]
    uint32_t* x_lds = (uint32_t*)(smem + XOFF_IT);   // [8i*32b][10] k-pairs

    const int cb = blockIdx.x;
    const int t  = threadIdx.x;
    const int w  = t >> 6, l = t & 63;
    const int bl = l & 31, h = l >> 5;
    const int j0 = w * 4;

    {
        const int b = t >> 5, i = (t >> 2) & 7, k4 = (t & 3) * 4;
        const float4 xv = *(const float4*)(x + ((size_t)b * NIN + cb * IPB + i) * DIN + k4);
        x_lds[(i * 32 + b) * 10 + (k4 >> 1)]     = pack_bf2(xv.x, xv.y);
        x_lds[(i * 32 + b) * 10 + (k4 >> 1) + 1] = pack_bf2(xv.z, xv.w);
    }
#pragma unroll 4
    for (int rep = 0; rep < 32; ++rep) {
        const int idx = rep * 1024 + t;
        const int b = idx >> 10, j = (idx >> 4) & 63, dp = idx & 15;
        const float2 vv = *(const float2*)(v_prev + ((size_t)b * NOUT + j) * DOUT + dp * 2);
        v_lds[(j * 16 + dp) * 33 + b] = pack_h2(vv.x, vv.y);
    }
    __syncthreads();

    f32x16 sacc[4];
#pragma unroll
    for (int jj = 0; jj < 4; ++jj) sacc[jj] = (f32x16)0.0f;

    constexpr int base_dp[8] = {0, 1, 4, 5, 8, 9, 12, 13};

#pragma unroll 1
    for (int i = 0; i < IPB; ++i) {
        const int ig = cb * IPB + i;
        const size_t wbase = (size_t)ig * WI;

        bf16x8 bfr;
        {
            uint32_t uu[4];
            const uint32_t* xp = &x_lds[(i * 32 + bl) * 10 + h * 4];
            uu[0] = xp[0]; uu[1] = xp[1]; uu[2] = xp[2]; uu[3] = xp[3];
            __builtin_memcpy(&bfr, uu, 16);
        }

        // ===== PHASE A: logits for this wave's 4 j =====
#pragma unroll
        for (int jj = 0; jj < 4; ++jj) {
            const int j = j0 + jj;
            const bf16x8 afr = *(const bf16x8*)(Wb + wbase + (size_t)(j * 32 + bl) * 16 + h * 8);
            const f32x16 D = __builtin_amdgcn_mfma_f32_32x32x16_bf16(afr, bfr, (f32x16)0.0f, 0, 0, 0);
            float acc = 0.f;
#pragma unroll
            for (int rp = 0; rp < 8; ++rp) {
                const int dp = base_dp[rp] + 2 * h;
                h2 dpk; dpk.x = (_Float16)D[2 * rp]; dpk.y = (_Float16)D[2 * rp + 1];
                acc = __builtin_amdgcn_fdot2(dpk, as_h2(v_lds[(j * 16 + dp) * 33 + bl]), acc, false);
            }
            acc += __shfl_xor(acc, 32);       // combine d-halves
            if (h == 0) c_lds[j * 33 + bl] = acc;
        }
        __syncthreads();

        // ===== PHASE B: softmax over j (32 b-rows, 2 per wave) =====
#pragma unroll
        for (int rr = 0; rr < 2; ++rr) {
            const int b = w * 2 + rr;
            float bv = c_lds[l * 33 + b];
            if (IT == 2) bv += blog_in[((size_t)b * NIN + ig) * NOUT + l];
            if (IT == 1) blog_out[((size_t)b * NIN + ig) * NOUT + l] = bv;
            float m = bv;
#pragma unroll
            for (int o = 32; o; o >>= 1) m = fmaxf(m, __shfl_xor(m, o));
            const float e = __expf(bv - m);
            float s = e;
#pragma unroll
            for (int o = 32; o; o >>= 1) s += __shfl_xor(s, o);
            c_lds[l * 33 + b] = e / s;
        }
        __syncthreads();

        // ===== PHASE C: accumulate (W_i re-read is L2-hot) =====
#pragma unroll
        for (int jj = 0; jj < 4; ++jj) {
            const int j = j0 + jj;
            const bf16x8 afr = *(const bf16x8*)(Wb + wbase + (size_t)(j * 32 + bl) * 16 + h * 8);
            const f32x16 D = __builtin_amdgcn_mfma_f32_32x32x16_bf16(afr, bfr, (f32x16)0.0f, 0, 0, 0);
            const float cv = c_lds[j * 33 + bl];      // c[b,i,j]: d-invariant
            sacc[jj] += D * cv;
        }
        __syncthreads();   // protect c_lds before next i's phase A
    }

    // ---- store partials: spart[cb][jd][b] bf16 ----
#pragma unroll
    for (int jj = 0; jj < 4; ++jj) {
        const int j = j0 + jj;
#pragma unroll
        for (int r = 0; r < 16; ++r) {
            const int d = (r & 3) + 8 * (r >> 2) + 4 * h;
            s_partial[(size_t)cb * (2048 * 32) + (size_t)(j * 32 + d) * 32 + bl] =
                f2bf(sacc[jj][r]);
        }
    }
}

// ---------------- reduce over cb + bias + squash (R11/R17 byte-identical) ----------------
__global__ __launch_bounds__(256) void caps_squash(
    const uint16_t* __restrict__ sp, const float* __restrict__ bias,
    float* __restrict__ vout)
{
    const int j  = blockIdx.x >> 2;
    const int bq = blockIdx.x & 3;
    const int t  = threadIdx.x;
    const int d  = t >> 3;
    const int blq = t & 7;
    const int b  = bq * 8 + blq;

    const uint16_t* p = sp + (size_t)(j * 32 + d) * 32 + b;
    float s0 = 0.f, s1 = 0.f, s2 = 0.f, s3 = 0.f;
#pragma unroll 4
    for (int c = 0; c < NCB; c += 4) {
        s0 += bf2f(p[(size_t)(c + 0) * (2048 * 32)]);
        s1 += bf2f(p[(size_t)(c + 1) * (2048 * 32)]);
        s2 += bf2f(p[(size_t)(c + 2) * (2048 * 32)]);
        s3 += bf2f(p[(size_t)(c + 3) * (2048 * 32)]);
    }
    const float sv = ((s0 + s1) + (s2 + s3)) + bias[j * DOUT + d];

    float sq = sv * sv;
    sq += __shfl_xor(sq, 8);
    sq += __shfl_xor(sq, 16);
    sq += __shfl_xor(sq, 32);

    __shared__ float sh[4][8];
    if ((t & 63) < 8) sh[t >> 6][t & 7] = sq;
    __syncthreads();
    const float tot = sh[0][blq] + sh[1][blq] + sh[2][blq] + sh[3][blq];
    const float scale = (tot / (1.0f + tot)) * rsqrtf(tot + 1e-9f);
    vout[(size_t)b * (NOUT * DOUT) + j * DOUT + d] = scale * sv;
}

extern "C" void kernel_launch(void* const* d_in, const int* in_sizes, int n_in,
                              void* d_out, int out_size, void* d_ws, size_t ws_size,
                              hipStream_t stream) {
    const float* x    = (const float*)d_in[0];
    const float* W    = (const float*)d_in[1];
    const float* bias = (const float*)d_in[2];
    float* out = (float*)d_out;

    // ws: Wh 134.22MB | blog 16.78MB | spart(bf16) 33.55MB | vbuf 0.26MB = 184.8MB
    char* base = (char*)d_ws;
    uint32_t* Wh    = (uint32_t*)base;
    float*    blog  = (float*)(base + WELEM * 2);
    uint16_t* spart = (uint16_t*)(base + WELEM * 2 + (size_t)CB * NIN * NOUT * 4);
    float*    vbuf  = (float*)(base + WELEM * 2 + (size_t)CB * NIN * NOUT * 4
                               + (size_t)NCB * 2048 * 32 * 2);
    (void)ws_size;

    hipFuncSetAttribute(reinterpret_cast<const void*>(caps_it<1>),
                        hipFuncAttributeMaxDynamicSharedMemorySize, SMEM_IT);
    hipFuncSetAttribute(reinterpret_cast<const void*>(caps_it<2>),
                        hipFuncAttributeMaxDynamicSharedMemorySize, SMEM_IT);

    caps_pass0<<<NCB * 2, 512, 0, stream>>>(x, W, Wh, spart);
    caps_squash<<<NOUT * 4, 256, 0, stream>>>(spart, bias, vbuf);

    caps_it<1><<<NCB, 1024, SMEM_IT, stream>>>(x, (const uint16_t*)Wh, vbuf, nullptr, blog, spart);
    caps_squash<<<NOUT * 4, 256, 0, stream>>>(spart, bias, vbuf);

    caps_it<2><<<NCB, 1024, SMEM_IT, stream>>>(x, (const uint16_t*)Wh, vbuf, blog, nullptr, spart);
    caps_squash<<<NOUT * 4, 256, 0, stream>>>(spart, bias, out);
}